// Round 21
// baseline (188.821 us; speedup 1.0000x reference)
//
#include <hip/hip_runtime.h>
#include <math.h>
#include <stdint.h>
#include <limits.h>

#define NPTS 32768
#define DIM  256
#define KCB  4096
#define NQ   (NPTS*DIM)

#define EPSN    1e-12f
#define MARGIN1 6.0e-4f
#define F16MIN  6.103515625e-05f
#define CAPB    4096
#define KINIT   0x7F800000FFFFFFFFull   /* packed (+INF, k=~0) */

typedef __attribute__((ext_vector_type(8))) _Float16 f16x8;
typedef __attribute__((ext_vector_type(4))) _Float16 f16x4;
typedef __attribute__((ext_vector_type(4))) float    f32x4;

// ws layout (byte offsets), all disjoint.
#define WS_EH0   0u         // KCB*DIM f16 (2MB)
#define WS_TRI   2097152u   // NPTS*4 ulonglong2 (2MB)
#define WS_SUME  4194304u   // KCB f32
#define WS_EINV  4210688u   // KCB f32
#define WS_XINV  4227072u   // NPTS f32 (ends 4358144)
#define WS_IDX   4358144u   // NPTS i32 (ends 4489216)
#define WS_RCB   4489216u   // 1 i32 (pad 16)
#define WS_RLB   4489232u   // CAPB i32 (16KB)
#define WS_BEST  4505616u   // CAPB u64 (32KB)
#define WS_LOSSP 4915232u   // 2048 f32

__device__ inline unsigned fbits(float f){ union{float f;unsigned u;}v; v.f=f; return v.u; }
__device__ inline float bitsf(unsigned u){ union{float f;unsigned u;}v; v.u=u; return v.f; }
__device__ inline uint64_t dbits(double d){ union{double d;uint64_t u;}v; v.d=d; return v.u; }
__device__ inline _Float16 g16(float v){
    return (fabsf(v) < F16MIN) ? (_Float16)0.0f : (_Float16)v;
}
__device__ inline void gload16(const void* src, void* lds){
    __builtin_amdgcn_global_load_lds((const __attribute__((address_space(1))) void*)src,
                                     (__attribute__((address_space(3))) void*)lds, 16, 0, 0);
}

// also zeroes the listB counter (block 0) and inits bestu (blocks 0..15)
__global__ __launch_bounds__(256) void k_norm_e(const float* __restrict__ e,
                                                _Float16* __restrict__ eh0,
                                                float* __restrict__ sume,
                                                float* __restrict__ einv,
                                                int* __restrict__ rcb,
                                                uint64_t* __restrict__ bestu) {
    if (blockIdx.x == 0 && threadIdx.x == 0) *rcb = 0;
    if (blockIdx.x < 16) bestu[blockIdx.x * 256 + threadIdx.x] = ~0ull;
    int w = threadIdx.x >> 6, l = threadIdx.x & 63;
    int row = blockIdx.x * 4 + w;
    float4 v = ((const float4*)e)[row * 64 + l];
    float s = v.x*v.x + v.y*v.y + v.z*v.z + v.w*v.w;
    #pragma unroll
    for (int o = 32; o; o >>= 1) s += __shfl_xor(s, o);
    float inv = 1.0f / fmaxf(sqrtf(s), EPSN);
    float4 n = make_float4(v.x*inv, v.y*inv, v.z*inv, v.w*inv);
    f16x4 h0; h0[0]=g16(n.x); h0[1]=g16(n.y); h0[2]=g16(n.z); h0[3]=g16(n.w);
    ((f16x4*)eh0)[row * 64 + l] = h0;
    float s2 = n.x*n.x + n.y*n.y + n.z*n.z + n.w*n.w;
    #pragma unroll
    for (int o = 32; o; o >>= 1) s2 += __shfl_xor(s2, o);
    if (l == 0) { sume[row] = s2; einv[row] = inv; }
}

// tier 1: swapped-operand f16 MFMA argmin, dhl-major conflict-free LDS,
// constant-bias (5.0) max-screened epilogue, zero-C acc init. K-split 4.
// NEW (r21): x row norms computed IN-KERNEL (lhi-lane shfl reduce over the
// A-fragment loads); split-0 blocks write xinv for tier-2. k_norm_x deleted.
// (Phase1 core is the 132us best. Split-8 regressed r18; branchless
// epilogue regressed r16; counted-vmcnt neutral r15. Do not touch core.)
// launch_bounds (256,2): (256,3) spilled (round 13, WRITE 31MB). Keep.
__global__ __launch_bounds__(256,2) void k_phase1(
    const float* __restrict__ x, float* __restrict__ xinv,
    const _Float16* __restrict__ eh0,
    ulonglong2* __restrict__ tri)
{
    __shared__ __align__(16) _Float16 Bs[2][32 * DIM];  // 2 x 16 KB
    const int tid = threadIdx.x;
    const int w = tid >> 6, l = tid & 63;
    const int l15 = l & 15, lhi = l >> 4;
    const int rowbase = (blockIdx.x >> 2) * 256 + w * 64;
    const int kbase   = (blockIdx.x & 3) * 1024;
    const int split   = blockIdx.x & 3;
    char* BsC = (char*)&Bs[0][0];

    // A (row) fragments with fused norm: lane loads its 64 dims of the row,
    // sumsq reduced across the 4 lhi lanes (shfl 16,32) -> full-row norm.
    f16x8 a[4][8];
    #pragma unroll
    for (int g = 0; g < 4; g++) {
        int row = rowbase + g*16 + l15;
        const float4* xr = (const float4*)(x + row * DIM);
        float4 fr[16];
        float s = 0.f;
        #pragma unroll
        for (int dc = 0; dc < 8; dc++) {
            float4 f0 = xr[dc*8 + lhi*2];
            float4 f1 = xr[dc*8 + lhi*2 + 1];
            fr[dc*2]   = f0;
            fr[dc*2+1] = f1;
            s += f0.x*f0.x + f0.y*f0.y + f0.z*f0.z + f0.w*f0.w
               + f1.x*f1.x + f1.y*f1.y + f1.z*f1.z + f1.w*f1.w;
        }
        s += __shfl_xor(s, 16);
        s += __shfl_xor(s, 32);
        float xv = 1.0f / fmaxf(sqrtf(s), EPSN);
        if (split == 0 && lhi == 0) xinv[row] = xv;   // each row written once
        #pragma unroll
        for (int dc = 0; dc < 8; dc++) {
            float4 f0 = fr[dc*2], f1 = fr[dc*2+1];
            f16x8 av;
            av[0]=g16(f0.x*xv); av[1]=g16(f0.y*xv);
            av[2]=g16(f0.z*xv); av[3]=g16(f0.w*xv);
            av[4]=g16(f1.x*xv); av[5]=g16(f1.y*xv);
            av[6]=g16(f1.z*xv); av[7]=g16(f1.w*xv);
            a[g][dc] = av;
        }
    }

    uint64_t t0[4], t1[4];
    float d2[4];
    #pragma unroll
    for (int g = 0; g < 4; g++) { t0[g]=KINIT; t1[g]=KINIT; d2[g]=INFINITY; }

    const char* sbase = (const char*)eh0 + (size_t)kbase * 512
                      + (size_t)(l & 31) * 512 + w*32 + (l >> 5)*16;
    auto stage = [&](int kt, int bufbyte) {
        const char* s = sbase + kt * 16384;
        #pragma unroll
        for (int p = 0; p < 4; p++) {
            gload16(s + p*128, BsC + bufbyte + ((p*256 + w*64) << 4));
        }
    };

    const int rb = lhi*512 + l15*16;
    const f32x4 zc = (f32x4){0.f, 0.f, 0.f, 0.f};

    auto compute = [&](int kt, int bufbyte) {
        f32x4 acc[4][2];
        #pragma unroll
        for (int dc = 0; dc < 8; dc++) {
            #pragma unroll
            for (int ni = 0; ni < 2; ni++) {
                f16x8 b = *(const f16x8*)(BsC + bufbyte + dc*2048 + ni*256 + rb);
                if (dc == 0) {
                    acc[0][ni] = __builtin_amdgcn_mfma_f32_16x16x32_f16(b, a[0][0], zc, 0, 0, 0);
                    acc[1][ni] = __builtin_amdgcn_mfma_f32_16x16x32_f16(b, a[1][0], zc, 0, 0, 0);
                    acc[2][ni] = __builtin_amdgcn_mfma_f32_16x16x32_f16(b, a[2][0], zc, 0, 0, 0);
                    acc[3][ni] = __builtin_amdgcn_mfma_f32_16x16x32_f16(b, a[3][0], zc, 0, 0, 0);
                } else {
                    acc[0][ni] = __builtin_amdgcn_mfma_f32_16x16x32_f16(b, a[0][dc], acc[0][ni], 0, 0, 0);
                    acc[1][ni] = __builtin_amdgcn_mfma_f32_16x16x32_f16(b, a[1][dc], acc[1][ni], 0, 0, 0);
                    acc[2][ni] = __builtin_amdgcn_mfma_f32_16x16x32_f16(b, a[2][dc], acc[2][ni], 0, 0, 0);
                    acc[3][ni] = __builtin_amdgcn_mfma_f32_16x16x32_f16(b, a[3][dc], acc[3][ni], 0, 0, 0);
                }
            }
        }

        #pragma unroll
        for (int ni = 0; ni < 2; ni++) {
            #pragma unroll
            for (int g = 0; g < 4; g++) {
                f32x4 v = acc[g][ni];
                float mx = fmaxf(fmaxf(v[0], v[1]), fmaxf(v[2], v[3]));
                if (5.0f - 2.0f*mx < d2[g]) {
                    #pragma unroll
                    for (int r = 0; r < 4; r++) {
                        float db = 5.0f - 2.0f*v[r];            // positive
                        if (db < d2[g]) {
                            int code = kbase + kt*32 + ni*16 + lhi*4 + r;
                            uint64_t key = ((uint64_t)fbits(db) << 32) | (unsigned)code;
                            if (key < t1[g]) {
                                d2[g] = bitsf((unsigned)(t1[g] >> 32));
                                if (key < t0[g]) { t1[g] = t0[g]; t0[g] = key; }
                                else t1[g] = key;
                            } else {
                                d2[g] = db;
                            }
                        }
                    }
                }
            }
        }
    };

    stage(0, 0);
    for (int kt = 0; kt < 32; kt += 2) {
        __syncthreads();
        stage(kt + 1, 16384);
        compute(kt, 0);
        __syncthreads();
        if (kt + 2 < 32) stage(kt + 2, 0);
        compute(kt + 1, 16384);
    }

    #pragma unroll
    for (int g = 0; g < 4; g++) {
        uint64_t a0 = t0[g], a1 = t1[g];
        float a2 = d2[g];
        #pragma unroll
        for (int m = 16; m < 64; m <<= 1) {
            uint64_t b0 = __shfl_xor(a0, m), b1 = __shfl_xor(a1, m);
            float    b2 = __shfl_xor(a2, m);
            uint64_t lo  = a0 < b0 ? a0 : b0;
            uint64_t hi0 = a0 < b0 ? b0 : a0;
            uint64_t lo1 = a1 < b1 ? a1 : b1;
            uint64_t mid = hi0 > lo1 ? hi0 : lo1;
            a1 = hi0 < lo1 ? hi0 : lo1;
            a0 = lo;
            a2 = fminf(fminf(a2, b2), bitsf((unsigned)(mid >> 32)));
        }
        t0[g] = a0; t1[g] = a1; d2[g] = a2;
    }

    if (lhi == 0) {
        #pragma unroll
        for (int g = 0; g < 4; g++) {
            int row = rowbase + g*16 + l15;
            float d0 = bitsf((unsigned)(t0[g] >> 32));
            uint64_t flag = (d2[g] - d0 < MARGIN1) ? (1ull << 12) : 0ull;
            ulonglong2 ent;
            ent.x = t0[g];
            ent.y = t1[g] | flag;
            tri[(row << 2) | split] = ent;
        }
    }
}

// fused merge + listA rescore. listB rows appended to GLOBAL rlb for the
// chunk-parallel k_full (r19 lesson: block-serial full-K f64 = 185us tail).
__global__ __launch_bounds__(256) void k_tailA(
    const ulonglong2* __restrict__ tri,
    const float* __restrict__ x, const float* __restrict__ emb,
    const float* __restrict__ xinv, const float* __restrict__ einv,
    const float* __restrict__ sume,
    int* __restrict__ idx,
    int* __restrict__ rcb, int* __restrict__ rlb)
{
    __shared__ int rowsA[256], ksA[256];
    __shared__ int cntA;
    const int tid = threadIdx.x;
    if (tid == 0) cntA = 0;
    __syncthreads();

    {   // merge phase: one thread per row
        int row = blockIdx.x * 256 + tid;
        ulonglong2 e0 = tri[row*4+0], e1 = tri[row*4+1],
                   e2 = tri[row*4+2], e3 = tri[row*4+3];
        uint64_t c0 = e0.x, c1 = e0.y & ~0x1000ull;
        float c2 = INFINITY;
        auto fold = [&](uint64_t b0, uint64_t b1) {
            b1 &= ~0x1000ull;
            uint64_t lo  = c0 < b0 ? c0 : b0;
            uint64_t hi0 = c0 < b0 ? b0 : c0;
            uint64_t lo1 = c1 < b1 ? c1 : b1;
            uint64_t mid = hi0 > lo1 ? hi0 : lo1;
            c1 = hi0 < lo1 ? hi0 : lo1;
            c0 = lo;
            c2 = fminf(c2, bitsf((unsigned)(mid >> 32)));
        };
        fold(e1.x, e1.y); fold(e2.x, e2.y); fold(e3.x, e3.y);
        int k0 = (int)((unsigned)c0 & 0xFFFu);
        idx[row] = k0;
        float d0 = bitsf((unsigned)(c0 >> 32));
        float d1 = bitsf((unsigned)(c1 >> 32));
        bool lA = (d1 - d0 < MARGIN1);
        bool lB = (c2 - d0 < MARGIN1);
        if ((e0.y >> 12) & 1) lB |= (bitsf((unsigned)(e0.x >> 32)) - d0 < MARGIN1);
        if ((e1.y >> 12) & 1) lB |= (bitsf((unsigned)(e1.x >> 32)) - d0 < MARGIN1);
        if ((e2.y >> 12) & 1) lB |= (bitsf((unsigned)(e2.x >> 32)) - d0 < MARGIN1);
        if ((e3.y >> 12) & 1) lB |= (bitsf((unsigned)(e3.x >> 32)) - d0 < MARGIN1);
        if (lA) {
            int k1 = (int)((unsigned)c1 & 0xFFFu);
            int p = atomicAdd(&cntA, 1);
            rowsA[p] = row; ksA[p] = k0 | (k1 << 12);
        }
        if (lB) {
            int q = atomicAdd(rcb, 1);
            if (q < CAPB) rlb[q] = row;
        }
    }
    __syncthreads();

    // listA: one wave per flagged row, exact f64 2-candidate rescore
    const int w = tid >> 6, l = tid & 63;
    const int nA = cntA;
    for (int i = w; i < nA; i += 4) {
        int row = rowsA[i];
        int k0 = ksA[i] & 0xFFF, k1 = (ksA[i] >> 12) & 0xFFF;
        float xv = xinv[row];
        float4 xf = ((const float4*)x)[row * 64 + l];
        double x0 = (double)xf.x * (double)xv, x1 = (double)xf.y * (double)xv;
        double x2 = (double)xf.z * (double)xv, x3 = (double)xf.w * (double)xv;
        int ks[2] = {k0, k1};
        double d[2];
        #pragma unroll
        for (int c = 0; c < 2; c++) {
            int k = ks[c];
            float ev = einv[k];
            float4 e4 = ((const float4*)emb)[k * 64 + l];
            d[c] = x0 * (double)(e4.x * ev) + x1 * (double)(e4.y * ev)
                 + x2 * (double)(e4.z * ev) + x3 * (double)(e4.w * ev);
        }
        #pragma unroll
        for (int o = 32; o; o >>= 1) {
            d[0] += __shfl_xor(d[0], o);
            d[1] += __shfl_xor(d[1], o);
        }
        if (l == 0) {
            double dist0 = 4.0 + (double)sume[k0] - 2.0 * d[0];
            double dist1 = 4.0 + (double)sume[k1] - 2.0 * d[1];
            uint64_t key0 = (dbits(dist0) & 0xFFFFFFFFFFFFF000ull) | (unsigned)k0;
            uint64_t key1 = (dbits(dist1) & 0xFFFFFFFFFFFFF000ull) | (unsigned)k1;
            idx[row] = (int)((key0 < key1 ? key0 : key1) & 0xFFFull);
        }
    }
}

// tier 2b: full-K f64 direct from emb, CHUNK-PARALLEL (16 blocks per row)
__global__ __launch_bounds__(256) void k_full(
    const float* __restrict__ x, const float* __restrict__ emb,
    const float* __restrict__ xinv, const float* __restrict__ einv,
    const float* __restrict__ sume,
    const int* __restrict__ rcb, const int* __restrict__ rlb,
    uint64_t* __restrict__ bestu)
{
    __shared__ __align__(16) float xs[DIM];
    int cnt = *rcb; if (cnt > CAPB) cnt = CAPB; if (cnt <= 0) return;
    const int tid = threadIdx.x;
    const int grp = tid >> 3, sub = tid & 7;
    int items = cnt * 16;
    for (int item = blockIdx.x; item < items; item += gridDim.x) {
        int r = item >> 4, chunk = item & 15;
        int row = rlb[r];
        __syncthreads();
        xs[tid] = x[row * DIM + tid] * xinv[row];
        __syncthreads();
        const float4* xs4 = (const float4*)xs;
        uint64_t best = ~0ull;
        #pragma unroll
        for (int j = 0; j < 8; j++) {
            int k = chunk * 256 + grp * 8 + j;
            float ev = einv[k];
            const float4* e4 = (const float4*)(emb + (size_t)k * DIM);
            double dp0 = 0, dp1 = 0;
            #pragma unroll
            for (int i = 0; i < 8; i += 2) {
                float4 ef0 = e4[sub + i*8];
                float4 xf0 = xs4[sub + i*8];
                float4 ef1 = e4[sub + (i+1)*8];
                float4 xf1 = xs4[sub + (i+1)*8];
                dp0 += (double)xf0.x * (double)(ef0.x * ev)
                     + (double)xf0.y * (double)(ef0.y * ev)
                     + (double)xf0.z * (double)(ef0.z * ev)
                     + (double)xf0.w * (double)(ef0.w * ev);
                dp1 += (double)xf1.x * (double)(ef1.x * ev)
                     + (double)xf1.y * (double)(ef1.y * ev)
                     + (double)xf1.z * (double)(ef1.z * ev)
                     + (double)xf1.w * (double)(ef1.w * ev);
            }
            double dp = dp0 + dp1;
            #pragma unroll
            for (int o = 4; o; o >>= 1) dp += __shfl_xor(dp, o);
            if (sub == 0) {
                double dist = 4.0 + (double)sume[k] - 2.0 * dp;
                uint64_t key = (dbits(dist) & 0xFFFFFFFFFFFFF000ull) | (unsigned)k;
                best = key < best ? key : best;
            }
        }
        if (sub == 0)
            atomicMin((unsigned long long*)&bestu[r], (unsigned long long)best);
    }
}

__global__ __launch_bounds__(256) void k_ffin(const int* __restrict__ rcb,
                                              const int* __restrict__ rlb,
                                              const uint64_t* __restrict__ bestu,
                                              int* __restrict__ idx) {
    int cnt = *rcb; if (cnt > CAPB) cnt = CAPB;
    int i = blockIdx.x * 256 + threadIdx.x;
    if (i < cnt) idx[rlb[i]] = (int)(bestu[i] & 0xFFFull);
}

// gather raw embeddings, straight-through output, loss partials, idx-as-float
__global__ __launch_bounds__(256) void k_gather(const float* __restrict__ x,
                                                const float* __restrict__ emb,
                                                const int* __restrict__ idx,
                                                float* __restrict__ out,
                                                float* __restrict__ lossp) {
    int t = blockIdx.x * 256 + threadIdx.x;
    float ls = 0.f;
    #pragma unroll
    for (int s = 0; s < 4; ++s) {
        int i4 = t + s * 524288;
        int n = i4 >> 6, c4 = i4 & 63;
        int id = idx[n];
        float4 f = ((const float4*)x)[i4];
        float4 q = ((const float4*)emb)[id * 64 + c4];
        float dx = q.x - f.x, dy = q.y - f.y, dz = q.z - f.z, dw = q.w - f.w;
        float4 o = make_float4(f.x + dx, f.y + dy, f.z + dz, f.w + dw);
        ((float4*)out)[i4] = o;
        ls += dx*dx + dy*dy + dz*dz + dw*dw;
        if (c4 == 0) out[NQ + 1 + n] = (float)id;
    }
    #pragma unroll
    for (int o = 32; o; o >>= 1) ls += __shfl_xor(ls, o);
    __shared__ float wsum[4];
    int wid = threadIdx.x >> 6, lane = threadIdx.x & 63;
    if (lane == 0) wsum[wid] = ls;
    __syncthreads();
    if (threadIdx.x == 0) lossp[blockIdx.x] = wsum[0] + wsum[1] + wsum[2] + wsum[3];
}

__global__ __launch_bounds__(256) void k_finalize(const float* __restrict__ lossp,
                                                  float* __restrict__ out) {
    double s = 0;
    for (int i = threadIdx.x; i < 2048; i += 256) s += (double)lossp[i];
    #pragma unroll
    for (int o = 32; o; o >>= 1) s += __shfl_xor(s, o);
    __shared__ double wd[4];
    int wid = threadIdx.x >> 6, lane = threadIdx.x & 63;
    if (lane == 0) wd[wid] = s;
    __syncthreads();
    if (threadIdx.x == 0)
        out[NQ] = (float)(0.25 * ((wd[0] + wd[1] + wd[2] + wd[3]) / (double)NQ));
}

extern "C" void kernel_launch(void* const* d_in, const int* in_sizes, int n_in,
                              void* d_out, int out_size, void* d_ws, size_t ws_size,
                              hipStream_t stream) {
    const float* x   = (const float*)d_in[0];
    const float* emb = (const float*)d_in[1];
    char* ws = (char*)d_ws;
    _Float16* eh0 = (_Float16*)(ws + WS_EH0);
    ulonglong2* tri = (ulonglong2*)(ws + WS_TRI);
    float* sume  = (float*)(ws + WS_SUME);
    float* einv  = (float*)(ws + WS_EINV);
    float* xinv  = (float*)(ws + WS_XINV);
    int*   idx   = (int*)  (ws + WS_IDX);
    int*   rcb   = (int*)  (ws + WS_RCB);
    int*   rlb   = (int*)  (ws + WS_RLB);
    uint64_t* bestu = (uint64_t*)(ws + WS_BEST);
    float* lossp = (float*)(ws + WS_LOSSP);
    float* out = (float*)d_out;

    hipLaunchKernelGGL(k_norm_e,   dim3(KCB/4),      dim3(256), 0, stream,
                       emb, eh0, sume, einv, rcb, bestu);
    hipLaunchKernelGGL(k_phase1,   dim3(NPTS/256*4), dim3(256), 0, stream,
                       x, xinv, eh0, tri);
    hipLaunchKernelGGL(k_tailA,    dim3(NPTS/256),   dim3(256), 0, stream,
                       tri, x, emb, xinv, einv, sume, idx, rcb, rlb);
    hipLaunchKernelGGL(k_full,     dim3(2048),       dim3(256), 0, stream,
                       x, emb, xinv, einv, sume, rcb, rlb, bestu);
    hipLaunchKernelGGL(k_ffin,     dim3(16),         dim3(256), 0, stream, rcb, rlb, bestu, idx);
    hipLaunchKernelGGL(k_gather,   dim3(2048),       dim3(256), 0, stream,
                       x, emb, idx, out, lossp);
    hipLaunchKernelGGL(k_finalize, dim3(1),          dim3(256), 0, stream, lossp, out);
}

// Round 22
// 170.956 us; speedup vs baseline: 1.1045x; 1.1045x over previous
//
#include <hip/hip_runtime.h>
#include <math.h>
#include <stdint.h>
#include <limits.h>

#define NPTS 32768
#define DIM  256
#define KCB  4096
#define NQ   (NPTS*DIM)

#define EPSN    1e-12f
#define MARGIN1 6.0e-4f
#define F16MIN  6.103515625e-05f
#define CAPB    4096
#define KINIT   0x7F800000FFFFFFFFull   /* packed (+INF, k=~0) */

typedef __attribute__((ext_vector_type(8))) _Float16 f16x8;
typedef __attribute__((ext_vector_type(4))) _Float16 f16x4;
typedef __attribute__((ext_vector_type(4))) float    f32x4;

// ws layout (byte offsets), all disjoint.
#define WS_EH0   0u         // KCB*DIM f16 (2MB)
#define WS_TRI   2097152u   // NPTS*4 ulonglong2 (2MB)
#define WS_SUME  4194304u   // KCB f32
#define WS_EINV  4210688u   // KCB f32
#define WS_XINV  4227072u   // NPTS f32 (ends 4358144)
#define WS_IDX   4358144u   // NPTS i32 (ends 4489216)
#define WS_RCB   4489216u   // 1 i32 (pad 16)
#define WS_RLB   4489232u   // CAPB i32 (16KB)
#define WS_BEST  4505616u   // CAPB u64 (32KB)
#define WS_LOSSP 4915232u   // 2048 f32

__device__ inline unsigned fbits(float f){ union{float f;unsigned u;}v; v.f=f; return v.u; }
__device__ inline float bitsf(unsigned u){ union{float f;unsigned u;}v; v.u=u; return v.f; }
__device__ inline uint64_t dbits(double d){ union{double d;uint64_t u;}v; v.d=d; return v.u; }
__device__ inline _Float16 g16(float v){
    return (fabsf(v) < F16MIN) ? (_Float16)0.0f : (_Float16)v;
}
__device__ inline void gload16(const void* src, void* lds){
    __builtin_amdgcn_global_load_lds((const __attribute__((address_space(1))) void*)src,
                                     (__attribute__((address_space(3))) void*)lds, 16, 0, 0);
}

// fused norms: blocks [0, NPTS/4) handle x rows (xinv only);
// blocks [NPTS/4, NPTS/4+KCB/4) handle codebook rows (eh0/sume/einv)
// plus counter/bestu init. Parts are independent; branch is block-uniform.
__global__ __launch_bounds__(256) void k_norm(const float* __restrict__ x,
                                              const float* __restrict__ e,
                                              float* __restrict__ xinv,
                                              _Float16* __restrict__ eh0,
                                              float* __restrict__ sume,
                                              float* __restrict__ einv,
                                              int* __restrict__ rcb,
                                              uint64_t* __restrict__ bestu) {
    int w = threadIdx.x >> 6, l = threadIdx.x & 63;
    if (blockIdx.x < NPTS/4) {
        int row = blockIdx.x * 4 + w;
        float4 v = ((const float4*)x)[row * 64 + l];
        float s = v.x*v.x + v.y*v.y + v.z*v.z + v.w*v.w;
        #pragma unroll
        for (int o = 32; o; o >>= 1) s += __shfl_xor(s, o);
        if (l == 0) xinv[row] = 1.0f / fmaxf(sqrtf(s), EPSN);
    } else {
        int eb = blockIdx.x - NPTS/4;
        if (eb == 0 && threadIdx.x == 0) *rcb = 0;
        if (eb < 16) bestu[eb * 256 + threadIdx.x] = ~0ull;
        int row = eb * 4 + w;
        float4 v = ((const float4*)e)[row * 64 + l];
        float s = v.x*v.x + v.y*v.y + v.z*v.z + v.w*v.w;
        #pragma unroll
        for (int o = 32; o; o >>= 1) s += __shfl_xor(s, o);
        float inv = 1.0f / fmaxf(sqrtf(s), EPSN);
        float4 n = make_float4(v.x*inv, v.y*inv, v.z*inv, v.w*inv);
        f16x4 h0; h0[0]=g16(n.x); h0[1]=g16(n.y); h0[2]=g16(n.z); h0[3]=g16(n.w);
        ((f16x4*)eh0)[row * 64 + l] = h0;
        float s2 = n.x*n.x + n.y*n.y + n.z*n.z + n.w*n.w;
        #pragma unroll
        for (int o = 32; o; o >>= 1) s2 += __shfl_xor(s2, o);
        if (l == 0) { sume[row] = s2; einv[row] = inv; }
    }
}

// tier 1: swapped-operand f16 MFMA argmin, dhl-major conflict-free LDS,
// constant-bias (5.0) max-screened epilogue, zero-C acc init. K-split 4.
// (Best measured 132us — r20 exact code. Fused-norm regressed r21 (VGPR
// 128 + scratch); split-8 regressed r18; branchless epilogue regressed
// r16; counted-vmcnt neutral r15. DO NOT TOUCH.)
// launch_bounds (256,2): (256,3) spilled (round 13, WRITE 31MB). Keep.
__global__ __launch_bounds__(256,2) void k_phase1(
    const float* __restrict__ x, const float* __restrict__ xinv,
    const _Float16* __restrict__ eh0,
    ulonglong2* __restrict__ tri)
{
    __shared__ __align__(16) _Float16 Bs[2][32 * DIM];  // 2 x 16 KB
    const int tid = threadIdx.x;
    const int w = tid >> 6, l = tid & 63;
    const int l15 = l & 15, lhi = l >> 4;
    const int rowbase = (blockIdx.x >> 2) * 256 + w * 64;
    const int kbase   = (blockIdx.x & 3) * 1024;
    char* BsC = (char*)&Bs[0][0];

    f16x8 a[4][8];
    #pragma unroll
    for (int g = 0; g < 4; g++) {
        int row = rowbase + g*16 + l15;
        float xv = xinv[row];
        const float4* xr = (const float4*)(x + row * DIM);
        #pragma unroll
        for (int dc = 0; dc < 8; dc++) {
            float4 f0 = xr[dc*8 + lhi*2];
            float4 f1 = xr[dc*8 + lhi*2 + 1];
            f16x8 av;
            av[0]=g16(f0.x*xv); av[1]=g16(f0.y*xv);
            av[2]=g16(f0.z*xv); av[3]=g16(f0.w*xv);
            av[4]=g16(f1.x*xv); av[5]=g16(f1.y*xv);
            av[6]=g16(f1.z*xv); av[7]=g16(f1.w*xv);
            a[g][dc] = av;
        }
    }

    uint64_t t0[4], t1[4];
    float d2[4];
    #pragma unroll
    for (int g = 0; g < 4; g++) { t0[g]=KINIT; t1[g]=KINIT; d2[g]=INFINITY; }

    const char* sbase = (const char*)eh0 + (size_t)kbase * 512
                      + (size_t)(l & 31) * 512 + w*32 + (l >> 5)*16;
    auto stage = [&](int kt, int bufbyte) {
        const char* s = sbase + kt * 16384;
        #pragma unroll
        for (int p = 0; p < 4; p++) {
            gload16(s + p*128, BsC + bufbyte + ((p*256 + w*64) << 4));
        }
    };

    const int rb = lhi*512 + l15*16;
    const f32x4 zc = (f32x4){0.f, 0.f, 0.f, 0.f};

    auto compute = [&](int kt, int bufbyte) {
        f32x4 acc[4][2];
        #pragma unroll
        for (int dc = 0; dc < 8; dc++) {
            #pragma unroll
            for (int ni = 0; ni < 2; ni++) {
                f16x8 b = *(const f16x8*)(BsC + bufbyte + dc*2048 + ni*256 + rb);
                if (dc == 0) {
                    acc[0][ni] = __builtin_amdgcn_mfma_f32_16x16x32_f16(b, a[0][0], zc, 0, 0, 0);
                    acc[1][ni] = __builtin_amdgcn_mfma_f32_16x16x32_f16(b, a[1][0], zc, 0, 0, 0);
                    acc[2][ni] = __builtin_amdgcn_mfma_f32_16x16x32_f16(b, a[2][0], zc, 0, 0, 0);
                    acc[3][ni] = __builtin_amdgcn_mfma_f32_16x16x32_f16(b, a[3][0], zc, 0, 0, 0);
                } else {
                    acc[0][ni] = __builtin_amdgcn_mfma_f32_16x16x32_f16(b, a[0][dc], acc[0][ni], 0, 0, 0);
                    acc[1][ni] = __builtin_amdgcn_mfma_f32_16x16x32_f16(b, a[1][dc], acc[1][ni], 0, 0, 0);
                    acc[2][ni] = __builtin_amdgcn_mfma_f32_16x16x32_f16(b, a[2][dc], acc[2][ni], 0, 0, 0);
                    acc[3][ni] = __builtin_amdgcn_mfma_f32_16x16x32_f16(b, a[3][dc], acc[3][ni], 0, 0, 0);
                }
            }
        }

        #pragma unroll
        for (int ni = 0; ni < 2; ni++) {
            #pragma unroll
            for (int g = 0; g < 4; g++) {
                f32x4 v = acc[g][ni];
                float mx = fmaxf(fmaxf(v[0], v[1]), fmaxf(v[2], v[3]));
                if (5.0f - 2.0f*mx < d2[g]) {
                    #pragma unroll
                    for (int r = 0; r < 4; r++) {
                        float db = 5.0f - 2.0f*v[r];            // positive
                        if (db < d2[g]) {
                            int code = kbase + kt*32 + ni*16 + lhi*4 + r;
                            uint64_t key = ((uint64_t)fbits(db) << 32) | (unsigned)code;
                            if (key < t1[g]) {
                                d2[g] = bitsf((unsigned)(t1[g] >> 32));
                                if (key < t0[g]) { t1[g] = t0[g]; t0[g] = key; }
                                else t1[g] = key;
                            } else {
                                d2[g] = db;
                            }
                        }
                    }
                }
            }
        }
    };

    stage(0, 0);
    for (int kt = 0; kt < 32; kt += 2) {
        __syncthreads();
        stage(kt + 1, 16384);
        compute(kt, 0);
        __syncthreads();
        if (kt + 2 < 32) stage(kt + 2, 0);
        compute(kt + 1, 16384);
    }

    #pragma unroll
    for (int g = 0; g < 4; g++) {
        uint64_t a0 = t0[g], a1 = t1[g];
        float a2 = d2[g];
        #pragma unroll
        for (int m = 16; m < 64; m <<= 1) {
            uint64_t b0 = __shfl_xor(a0, m), b1 = __shfl_xor(a1, m);
            float    b2 = __shfl_xor(a2, m);
            uint64_t lo  = a0 < b0 ? a0 : b0;
            uint64_t hi0 = a0 < b0 ? b0 : a0;
            uint64_t lo1 = a1 < b1 ? a1 : b1;
            uint64_t mid = hi0 > lo1 ? hi0 : lo1;
            a1 = hi0 < lo1 ? hi0 : lo1;
            a0 = lo;
            a2 = fminf(fminf(a2, b2), bitsf((unsigned)(mid >> 32)));
        }
        t0[g] = a0; t1[g] = a1; d2[g] = a2;
    }

    if (lhi == 0) {
        const int split = blockIdx.x & 3;
        #pragma unroll
        for (int g = 0; g < 4; g++) {
            int row = rowbase + g*16 + l15;
            float d0 = bitsf((unsigned)(t0[g] >> 32));
            uint64_t flag = (d2[g] - d0 < MARGIN1) ? (1ull << 12) : 0ull;
            ulonglong2 ent;
            ent.x = t0[g];
            ent.y = t1[g] | flag;
            tri[(row << 2) | split] = ent;
        }
    }
}

// fused merge + listA rescore. listB rows appended to GLOBAL rlb for the
// chunk-parallel k_full (r19 lesson: block-serial full-K f64 = 185us tail).
__global__ __launch_bounds__(256) void k_tailA(
    const ulonglong2* __restrict__ tri,
    const float* __restrict__ x, const float* __restrict__ emb,
    const float* __restrict__ xinv, const float* __restrict__ einv,
    const float* __restrict__ sume,
    int* __restrict__ idx,
    int* __restrict__ rcb, int* __restrict__ rlb)
{
    __shared__ int rowsA[256], ksA[256];
    __shared__ int cntA;
    const int tid = threadIdx.x;
    if (tid == 0) cntA = 0;
    __syncthreads();

    {   // merge phase: one thread per row
        int row = blockIdx.x * 256 + tid;
        ulonglong2 e0 = tri[row*4+0], e1 = tri[row*4+1],
                   e2 = tri[row*4+2], e3 = tri[row*4+3];
        uint64_t c0 = e0.x, c1 = e0.y & ~0x1000ull;
        float c2 = INFINITY;
        auto fold = [&](uint64_t b0, uint64_t b1) {
            b1 &= ~0x1000ull;
            uint64_t lo  = c0 < b0 ? c0 : b0;
            uint64_t hi0 = c0 < b0 ? b0 : c0;
            uint64_t lo1 = c1 < b1 ? c1 : b1;
            uint64_t mid = hi0 > lo1 ? hi0 : lo1;
            c1 = hi0 < lo1 ? hi0 : lo1;
            c0 = lo;
            c2 = fminf(c2, bitsf((unsigned)(mid >> 32)));
        };
        fold(e1.x, e1.y); fold(e2.x, e2.y); fold(e3.x, e3.y);
        int k0 = (int)((unsigned)c0 & 0xFFFu);
        idx[row] = k0;
        float d0 = bitsf((unsigned)(c0 >> 32));
        float d1 = bitsf((unsigned)(c1 >> 32));
        bool lA = (d1 - d0 < MARGIN1);
        bool lB = (c2 - d0 < MARGIN1);
        if ((e0.y >> 12) & 1) lB |= (bitsf((unsigned)(e0.x >> 32)) - d0 < MARGIN1);
        if ((e1.y >> 12) & 1) lB |= (bitsf((unsigned)(e1.x >> 32)) - d0 < MARGIN1);
        if ((e2.y >> 12) & 1) lB |= (bitsf((unsigned)(e2.x >> 32)) - d0 < MARGIN1);
        if ((e3.y >> 12) & 1) lB |= (bitsf((unsigned)(e3.x >> 32)) - d0 < MARGIN1);
        if (lA) {
            int k1 = (int)((unsigned)c1 & 0xFFFu);
            int p = atomicAdd(&cntA, 1);
            rowsA[p] = row; ksA[p] = k0 | (k1 << 12);
        }
        if (lB) {
            int q = atomicAdd(rcb, 1);
            if (q < CAPB) rlb[q] = row;
        }
    }
    __syncthreads();

    // listA: one wave per flagged row, exact f64 2-candidate rescore
    const int w = tid >> 6, l = tid & 63;
    const int nA = cntA;
    for (int i = w; i < nA; i += 4) {
        int row = rowsA[i];
        int k0 = ksA[i] & 0xFFF, k1 = (ksA[i] >> 12) & 0xFFF;
        float xv = xinv[row];
        float4 xf = ((const float4*)x)[row * 64 + l];
        double x0 = (double)xf.x * (double)xv, x1 = (double)xf.y * (double)xv;
        double x2 = (double)xf.z * (double)xv, x3 = (double)xf.w * (double)xv;
        int ks[2] = {k0, k1};
        double d[2];
        #pragma unroll
        for (int c = 0; c < 2; c++) {
            int k = ks[c];
            float ev = einv[k];
            float4 e4 = ((const float4*)emb)[k * 64 + l];
            d[c] = x0 * (double)(e4.x * ev) + x1 * (double)(e4.y * ev)
                 + x2 * (double)(e4.z * ev) + x3 * (double)(e4.w * ev);
        }
        #pragma unroll
        for (int o = 32; o; o >>= 1) {
            d[0] += __shfl_xor(d[0], o);
            d[1] += __shfl_xor(d[1], o);
        }
        if (l == 0) {
            double dist0 = 4.0 + (double)sume[k0] - 2.0 * d[0];
            double dist1 = 4.0 + (double)sume[k1] - 2.0 * d[1];
            uint64_t key0 = (dbits(dist0) & 0xFFFFFFFFFFFFF000ull) | (unsigned)k0;
            uint64_t key1 = (dbits(dist1) & 0xFFFFFFFFFFFFF000ull) | (unsigned)k1;
            idx[row] = (int)((key0 < key1 ? key0 : key1) & 0xFFFull);
        }
    }
}

// tier 2b: full-K f64 direct from emb, CHUNK-PARALLEL (16 blocks per row)
__global__ __launch_bounds__(256) void k_full(
    const float* __restrict__ x, const float* __restrict__ emb,
    const float* __restrict__ xinv, const float* __restrict__ einv,
    const float* __restrict__ sume,
    const int* __restrict__ rcb, const int* __restrict__ rlb,
    uint64_t* __restrict__ bestu)
{
    __shared__ __align__(16) float xs[DIM];
    int cnt = *rcb; if (cnt > CAPB) cnt = CAPB; if (cnt <= 0) return;
    const int tid = threadIdx.x;
    const int grp = tid >> 3, sub = tid & 7;
    int items = cnt * 16;
    for (int item = blockIdx.x; item < items; item += gridDim.x) {
        int r = item >> 4, chunk = item & 15;
        int row = rlb[r];
        __syncthreads();
        xs[tid] = x[row * DIM + tid] * xinv[row];
        __syncthreads();
        const float4* xs4 = (const float4*)xs;
        uint64_t best = ~0ull;
        #pragma unroll
        for (int j = 0; j < 8; j++) {
            int k = chunk * 256 + grp * 8 + j;
            float ev = einv[k];
            const float4* e4 = (const float4*)(emb + (size_t)k * DIM);
            double dp0 = 0, dp1 = 0;
            #pragma unroll
            for (int i = 0; i < 8; i += 2) {
                float4 ef0 = e4[sub + i*8];
                float4 xf0 = xs4[sub + i*8];
                float4 ef1 = e4[sub + (i+1)*8];
                float4 xf1 = xs4[sub + (i+1)*8];
                dp0 += (double)xf0.x * (double)(ef0.x * ev)
                     + (double)xf0.y * (double)(ef0.y * ev)
                     + (double)xf0.z * (double)(ef0.z * ev)
                     + (double)xf0.w * (double)(ef0.w * ev);
                dp1 += (double)xf1.x * (double)(ef1.x * ev)
                     + (double)xf1.y * (double)(ef1.y * ev)
                     + (double)xf1.z * (double)(ef1.z * ev)
                     + (double)xf1.w * (double)(ef1.w * ev);
            }
            double dp = dp0 + dp1;
            #pragma unroll
            for (int o = 4; o; o >>= 1) dp += __shfl_xor(dp, o);
            if (sub == 0) {
                double dist = 4.0 + (double)sume[k] - 2.0 * dp;
                uint64_t key = (dbits(dist) & 0xFFFFFFFFFFFFF000ull) | (unsigned)k;
                best = key < best ? key : best;
            }
        }
        if (sub == 0)
            atomicMin((unsigned long long*)&bestu[r], (unsigned long long)best);
    }
}

__global__ __launch_bounds__(256) void k_ffin(const int* __restrict__ rcb,
                                              const int* __restrict__ rlb,
                                              const uint64_t* __restrict__ bestu,
                                              int* __restrict__ idx) {
    int cnt = *rcb; if (cnt > CAPB) cnt = CAPB;
    int i = blockIdx.x * 256 + threadIdx.x;
    if (i < cnt) idx[rlb[i]] = (int)(bestu[i] & 0xFFFull);
}

// gather raw embeddings, straight-through output, loss partials, idx-as-float
__global__ __launch_bounds__(256) void k_gather(const float* __restrict__ x,
                                                const float* __restrict__ emb,
                                                const int* __restrict__ idx,
                                                float* __restrict__ out,
                                                float* __restrict__ lossp) {
    int t = blockIdx.x * 256 + threadIdx.x;
    float ls = 0.f;
    #pragma unroll
    for (int s = 0; s < 4; ++s) {
        int i4 = t + s * 524288;
        int n = i4 >> 6, c4 = i4 & 63;
        int id = idx[n];
        float4 f = ((const float4*)x)[i4];
        float4 q = ((const float4*)emb)[id * 64 + c4];
        float dx = q.x - f.x, dy = q.y - f.y, dz = q.z - f.z, dw = q.w - f.w;
        float4 o = make_float4(f.x + dx, f.y + dy, f.z + dz, f.w + dw);
        ((float4*)out)[i4] = o;
        ls += dx*dx + dy*dy + dz*dz + dw*dw;
        if (c4 == 0) out[NQ + 1 + n] = (float)id;
    }
    #pragma unroll
    for (int o = 32; o; o >>= 1) ls += __shfl_xor(ls, o);
    __shared__ float wsum[4];
    int wid = threadIdx.x >> 6, lane = threadIdx.x & 63;
    if (lane == 0) wsum[wid] = ls;
    __syncthreads();
    if (threadIdx.x == 0) lossp[blockIdx.x] = wsum[0] + wsum[1] + wsum[2] + wsum[3];
}

__global__ __launch_bounds__(256) void k_finalize(const float* __restrict__ lossp,
                                                  float* __restrict__ out) {
    double s = 0;
    for (int i = threadIdx.x; i < 2048; i += 256) s += (double)lossp[i];
    #pragma unroll
    for (int o = 32; o; o >>= 1) s += __shfl_xor(s, o);
    __shared__ double wd[4];
    int wid = threadIdx.x >> 6, lane = threadIdx.x & 63;
    if (lane == 0) wd[wid] = s;
    __syncthreads();
    if (threadIdx.x == 0)
        out[NQ] = (float)(0.25 * ((wd[0] + wd[1] + wd[2] + wd[3]) / (double)NQ));
}

extern "C" void kernel_launch(void* const* d_in, const int* in_sizes, int n_in,
                              void* d_out, int out_size, void* d_ws, size_t ws_size,
                              hipStream_t stream) {
    const float* x   = (const float*)d_in[0];
    const float* emb = (const float*)d_in[1];
    char* ws = (char*)d_ws;
    _Float16* eh0 = (_Float16*)(ws + WS_EH0);
    ulonglong2* tri = (ulonglong2*)(ws + WS_TRI);
    float* sume  = (float*)(ws + WS_SUME);
    float* einv  = (float*)(ws + WS_EINV);
    float* xinv  = (float*)(ws + WS_XINV);
    int*   idx   = (int*)  (ws + WS_IDX);
    int*   rcb   = (int*)  (ws + WS_RCB);
    int*   rlb   = (int*)  (ws + WS_RLB);
    uint64_t* bestu = (uint64_t*)(ws + WS_BEST);
    float* lossp = (float*)(ws + WS_LOSSP);
    float* out = (float*)d_out;

    hipLaunchKernelGGL(k_norm,     dim3(NPTS/4 + KCB/4), dim3(256), 0, stream,
                       x, emb, xinv, eh0, sume, einv, rcb, bestu);
    hipLaunchKernelGGL(k_phase1,   dim3(NPTS/256*4),     dim3(256), 0, stream,
                       x, xinv, eh0, tri);
    hipLaunchKernelGGL(k_tailA,    dim3(NPTS/256),       dim3(256), 0, stream,
                       tri, x, emb, xinv, einv, sume, idx, rcb, rlb);
    hipLaunchKernelGGL(k_full,     dim3(2048),           dim3(256), 0, stream,
                       x, emb, xinv, einv, sume, rcb, rlb, bestu);
    hipLaunchKernelGGL(k_ffin,     dim3(16),             dim3(256), 0, stream, rcb, rlb, bestu, idx);
    hipLaunchKernelGGL(k_gather,   dim3(2048),           dim3(256), 0, stream,
                       x, emb, idx, out, lossp);
    hipLaunchKernelGGL(k_finalize, dim3(1),              dim3(256), 0, stream, lossp, out);
}